// Round 1
// baseline (88.231 us; speedup 1.0000x reference)
//
#include <hip/hip_runtime.h>

// CNS residuals: vars (B=8, C=4, T=64, X=128, Y=128) f32
// out (B=8, 2, 62, 126, 126) f32: [mass, mom_x+mom_y] on inner region.
// d1/d2 are zero-padded central differences; only div-derivatives reach
// +-2 offsets which may fall out of range -> read as 0.

#define TS 64
#define XS 128
#define YS 128

__device__ __forceinline__ float ld(const float* __restrict__ p, int x, int y) {
    if ((unsigned)x >= (unsigned)XS || (unsigned)y >= (unsigned)YS) return 0.0f;
    return p[(x << 7) + y];
}

__global__ __launch_bounds__(128) void cns_residuals_kernel(
    const float* __restrict__ vars,
    const float* __restrict__ s_dx, const float* __restrict__ s_dt,
    const float* __restrict__ s_eta, const float* __restrict__ s_zeta,
    float* __restrict__ out)
{
    const float dx = s_dx[0], dt = s_dt[0], eta = s_eta[0], zeta = s_zeta[0];
    const float bulk = zeta + eta * (1.0f / 3.0f);
    const float c1 = 2.0f * dx * dx;   // rho*Dt term
    const float c2 = 2.0f * dt * dx;   // advection + pressure
    const float c3 = 4.0f * dt;        // viscous laplacian
    const float c4 = 2.0f * dt;        // bulk div term

    const int yp = threadIdx.x;
    if (yp >= 126) return;
    int bid = blockIdx.x;
    const int xp = bid % 126; bid /= 126;
    const int tp = bid % 62;  const int b = bid / 62;
    const int x = xp + 1, t = tp + 1, y = yp + 1;

    const size_t plane = (size_t)XS * YS;        // 16384
    const size_t cstr  = (size_t)TS * plane;     // per-channel stride
    const float* base = vars + (size_t)b * 4 * cstr + (size_t)t * plane;
    const float* R0 = base + 0 * cstr;
    const float* U0 = base + 1 * cstr;
    const float* V0 = base + 2 * cstr;
    const float* P0 = base + 3 * cstr;
    const float* Rm = R0 - plane; const float* Rp = R0 + plane;
    const float* Um = U0 - plane; const float* Up = U0 + plane;
    const float* Vm = V0 - plane; const float* Vp = V0 + plane;

    const float rho = ld(R0, x, y);
    const float u   = ld(U0, x, y);
    const float v   = ld(V0, x, y);

    const float Dt_rho = ld(Rp, x, y) - ld(Rm, x, y);
    const float Dx_rho = ld(R0, x + 1, y) - ld(R0, x - 1, y);
    const float Dy_rho = ld(R0, x, y + 1) - ld(R0, x, y - 1);

    const float uxp = ld(U0, x + 1, y), uxm = ld(U0, x - 1, y);
    const float uyp = ld(U0, x, y + 1), uym = ld(U0, x, y - 1);
    const float vxp = ld(V0, x + 1, y), vxm = ld(V0, x - 1, y);
    const float vyp = ld(V0, x, y + 1), vym = ld(V0, x, y - 1);

    const float Dt_u = ld(Up, x, y) - ld(Um, x, y);
    const float Dt_v = ld(Vp, x, y) - ld(Vm, x, y);
    const float Dx_u = uxp - uxm, Dy_u = uyp - uym;
    const float Dx_v = vxp - vxm, Dy_v = vyp - vym;
    const float Dx_p = ld(P0, x + 1, y) - ld(P0, x - 1, y);
    const float Dy_p = ld(P0, x, y + 1) - ld(P0, x, y - 1);

    const float lap_u = uxp + uxm + uyp + uym - 4.0f * u;
    const float lap_v = vxp + vxm + vyp + vym - 4.0f * v;

    // div = D_x(u) + D_y(v) over the full (padded) grid; these are d1 of that.
    const float Dx_div = ld(U0, x + 2, y) - 2.0f * u + ld(U0, x - 2, y)
                       + ld(V0, x + 1, y + 1) - ld(V0, x + 1, y - 1)
                       - ld(V0, x - 1, y + 1) + ld(V0, x - 1, y - 1);
    const float Dy_div = ld(V0, x, y + 2) - 2.0f * v + ld(V0, x, y - 2)
                       + ld(U0, x + 1, y + 1) - ld(U0, x - 1, y + 1)
                       - ld(U0, x + 1, y - 1) + ld(U0, x - 1, y - 1);

    const float mass = Dt_rho * dx + rho * (Dx_u + Dy_v) * dt
                     + u * Dx_rho * dt + v * Dy_rho * dt;

    const float mom_x = rho * Dt_u * c1 + u * Dx_u * c2 + v * Dy_u * c2
                      + Dx_p * c2 - eta * lap_u * c3 - bulk * Dx_div * c4;
    const float mom_y = rho * Dt_v * c1 + u * Dx_v * c2 + v * Dy_v * c2
                      + Dy_p * c2 - eta * lap_v * c3 - bulk * Dy_div * c4;

    const size_t oplane = 126 * 126;
    const size_t ocstr  = (size_t)62 * oplane;
    const size_t o = (size_t)b * 2 * ocstr + (size_t)tp * oplane
                   + (size_t)xp * 126 + yp;
    out[o]         = mass;
    out[o + ocstr] = mom_x + mom_y;
}

extern "C" void kernel_launch(void* const* d_in, const int* in_sizes, int n_in,
                              void* d_out, int out_size, void* d_ws, size_t ws_size,
                              hipStream_t stream) {
    const float* vars  = (const float*)d_in[0];
    const float* s_dx  = (const float*)d_in[1];
    const float* s_dt  = (const float*)d_in[2];
    const float* s_eta = (const float*)d_in[3];
    const float* s_zeta= (const float*)d_in[4];
    float* out = (float*)d_out;

    const int grid = 8 * 62 * 126;  // b * t' * x'
    hipLaunchKernelGGL(cns_residuals_kernel, dim3(grid), dim3(128), 0, stream,
                       vars, s_dx, s_dt, s_eta, s_zeta, out);
}

// Round 2
// 44.680 us; speedup vs baseline: 1.9747x; 1.9747x over previous
//
#include <hip/hip_runtime.h>

// CNS residuals: vars (B=8, C=4, T=64, X=128, Y=128) f32
// out (B=8, 2, 62, 126, 126) f32: [mass, mom_x+mom_y] on inner region.
// Each thread computes 4 consecutive y-outputs via register windows:
// 8-float y-window per stencil row = 2 unaligned dwordx4 loads; all y-shifts
// are shufflevector extracts. 28 vector loads / 4 outputs (vs 37 scalar/output).

typedef float vf4 __attribute__((ext_vector_type(4)));
typedef float vf4u __attribute__((ext_vector_type(4), aligned(4)));

__device__ __forceinline__ vf4 ld4(const float* __restrict__ p) {
    return *reinterpret_cast<const vf4u*>(p);
}

// shifted vector: element e = window value at y' = ybase + e + s
#define SH(lo, hi, s) __builtin_shufflevector(lo, hi, 2 + (s), 3 + (s), 4 + (s), 5 + (s))

__global__ __launch_bounds__(256) void cns_residuals_kernel(
    const float* __restrict__ vars,
    const float* __restrict__ s_dx, const float* __restrict__ s_dt,
    const float* __restrict__ s_eta, const float* __restrict__ s_zeta,
    float* __restrict__ out)
{
    const float dx = s_dx[0], dt = s_dt[0], eta = s_eta[0], zeta = s_zeta[0];
    const float bulk = zeta + eta * (1.0f / 3.0f);
    const float c1 = 2.0f * dx * dx;
    const float c2 = 2.0f * dt * dx;
    const float c3 = 4.0f * dt;
    const float c4 = 2.0f * dt;

    const int tid = blockIdx.x * 256 + threadIdx.x;
    const int j = tid & 31;            // y-group: outputs y = 1+4j .. 4+4j
    int r = tid >> 5;
    const int xp = r % 126; r /= 126;
    const int tp = r % 62;  const int b = r / 62;
    const int x = xp + 1, t = tp + 1;
    const int yb = 1 + 4 * j;

    const size_t plane = 16384;                 // 128*128
    const size_t cstr  = (size_t)64 * plane;    // per-channel stride

    // per-thread centered base: channel 0, plane t, row x, col yb
    const float* base = vars + (size_t)b * 4 * cstr + (size_t)t * plane
                      + ((size_t)x << 7) + yb;
    const float* R0 = base;
    const float* U0 = base + cstr;
    const float* V0 = base + 2 * cstr;
    const float* P0 = base + 3 * cstr;

    const float mLo = (j == 0)  ? 0.0f : 1.0f;   // y' = -1 must read 0
    const float mHi = (j == 31) ? 0.0f : 1.0f;   // y' >= 128 must read 0

    // 8-float y-window: lo covers y' = yb-2..yb+1, hi covers yb+2..yb+5
#define WIN(ptr, off, lo, hi) \
    vf4 lo = ld4((ptr) + (off) - 2); vf4 hi = ld4((ptr) + (off) + 2); \
    lo[0] *= mLo; hi[1] *= mHi; hi[2] *= mHi; hi[3] *= mHi;

    WIN(R0, 0,    r0lo, r0hi)
    WIN(U0, 0,    u0lo, u0hi)
    WIN(U0, 128,  uplo, uphi)
    WIN(U0, -128, umlo, umhi)
    WIN(V0, 0,    v0lo, v0hi)
    WIN(V0, 128,  vplo, vphi)
    WIN(V0, -128, vmlo, vmhi)
    WIN(P0, 0,    p0lo, p0hi)
#undef WIN

    // center-only loads (no y-shift needed)
    const vf4 rxp = ld4(R0 + 128), rxm = ld4(R0 - 128);
    const vf4 rtp = ld4(R0 + plane), rtm = ld4(R0 - plane);
    const vf4 utp = ld4(U0 + plane), utm = ld4(U0 - plane);
    const vf4 vtp = ld4(V0 + plane), vtm = ld4(V0 - plane);
    const vf4 pxp = ld4(P0 + 128), pxm = ld4(P0 - 128);
    const vf4 zero = {0.0f, 0.0f, 0.0f, 0.0f};
    const vf4 uxp2 = (x <= 125) ? ld4(U0 + 256) : zero;  // x+2 <= 127
    const vf4 uxm2 = (x >= 2)   ? ld4(U0 - 256) : zero;  // x-2 >= 0

    const vf4 rho = SH(r0lo, r0hi, 0);
    const vf4 u   = SH(u0lo, u0hi, 0);
    const vf4 v   = SH(v0lo, v0hi, 0);

    const vf4 uxp = SH(uplo, uphi, 0), uxm = SH(umlo, umhi, 0);
    const vf4 uyp = SH(u0lo, u0hi, 1), uym = SH(u0lo, u0hi, -1);
    const vf4 vxp = SH(vplo, vphi, 0), vxm = SH(vmlo, vmhi, 0);
    const vf4 vyp = SH(v0lo, v0hi, 1), vym = SH(v0lo, v0hi, -1);

    const vf4 Dt_rho = rtp - rtm;
    const vf4 Dx_rho = rxp - rxm;
    const vf4 Dy_rho = SH(r0lo, r0hi, 1) - SH(r0lo, r0hi, -1);
    const vf4 Dx_u = uxp - uxm, Dy_u = uyp - uym;
    const vf4 Dx_v = vxp - vxm, Dy_v = vyp - vym;

    const vf4 mass = Dt_rho * dx + rho * (Dx_u + Dy_v) * dt
                   + u * Dx_rho * dt + v * Dy_rho * dt;

    const vf4 Dt_u = utp - utm, Dt_v = vtp - vtm;
    const vf4 Dx_p = pxp - pxm;
    const vf4 Dy_p = SH(p0lo, p0hi, 1) - SH(p0lo, p0hi, -1);
    const vf4 lap_u = uxp + uxm + uyp + uym - 4.0f * u;
    const vf4 lap_v = vxp + vxm + vyp + vym - 4.0f * v;

    const vf4 Dx_div = uxp2 - 2.0f * u + uxm2
                     + SH(vplo, vphi, 1) - SH(vplo, vphi, -1)
                     - SH(vmlo, vmhi, 1) + SH(vmlo, vmhi, -1);
    const vf4 Dy_div = SH(v0lo, v0hi, 2) - 2.0f * v + SH(v0lo, v0hi, -2)
                     + SH(uplo, uphi, 1) - SH(umlo, umhi, 1)
                     - SH(uplo, uphi, -1) + SH(umlo, umhi, -1);

    const vf4 mom = rho * (Dt_u + Dt_v) * c1
                  + (u * Dx_u + v * Dy_u + u * Dx_v + v * Dy_v) * c2
                  + (Dx_p + Dy_p) * c2
                  - eta * (lap_u + lap_v) * c3
                  - bulk * (Dx_div + Dy_div) * c4;

    const size_t oplane = 126 * 126;
    const size_t ocstr  = (size_t)62 * oplane;
    float* o1 = out + (size_t)b * 2 * ocstr + (size_t)tp * oplane
              + (size_t)xp * 126 + 4 * j;
    float* o2 = o1 + ocstr;
    if (j < 31) {
        *reinterpret_cast<vf4u*>(o1) = mass;
        *reinterpret_cast<vf4u*>(o2) = mom;
    } else {  // outputs y=127,128 are out of range; store only 2
        o1[0] = mass[0]; o1[1] = mass[1];
        o2[0] = mom[0];  o2[1] = mom[1];
    }
}

extern "C" void kernel_launch(void* const* d_in, const int* in_sizes, int n_in,
                              void* d_out, int out_size, void* d_ws, size_t ws_size,
                              hipStream_t stream) {
    const float* vars   = (const float*)d_in[0];
    const float* s_dx   = (const float*)d_in[1];
    const float* s_dt   = (const float*)d_in[2];
    const float* s_eta  = (const float*)d_in[3];
    const float* s_zeta = (const float*)d_in[4];
    float* out = (float*)d_out;

    // total threads = 8 * 62 * 126 * 32 = 1,999,872 = 7812 blocks * 256
    const int grid = 7812;
    hipLaunchKernelGGL(cns_residuals_kernel, dim3(grid), dim3(256), 0, stream,
                       vars, s_dx, s_dt, s_eta, s_zeta, out);
}

// Round 3
// 39.978 us; speedup vs baseline: 2.2070x; 1.1176x over previous
//
#include <hip/hip_runtime.h>

// CNS residuals: vars (B=8, C=4, T=64, X=128, Y=128) f32
// out (B=8, 2, 62, 126, 126) f32: [mass, mom_x+mom_y] on inner region.
// y-vectorized by 4 (register windows, shufflevector shifts).
// R3: + XCD-chunked bijective block swizzle (each XCD ~ one batch b ->
//     t-plane reuse fits per-XCD 4MB L2) + nontemporal output stores
//     (63MB write-only stream stops evicting stencil data from L2/L3).

typedef float vf4 __attribute__((ext_vector_type(4)));
typedef float vf4u __attribute__((ext_vector_type(4), aligned(4)));

__device__ __forceinline__ vf4 ld4(const float* __restrict__ p) {
    return *reinterpret_cast<const vf4u*>(p);
}

#define SH(lo, hi, s) __builtin_shufflevector(lo, hi, 2 + (s), 3 + (s), 4 + (s), 5 + (s))

__global__ __launch_bounds__(256) void cns_residuals_kernel(
    const float* __restrict__ vars,
    const float* __restrict__ s_dx, const float* __restrict__ s_dt,
    const float* __restrict__ s_eta, const float* __restrict__ s_zeta,
    float* __restrict__ out)
{
    const float dx = s_dx[0], dt = s_dt[0], eta = s_eta[0], zeta = s_zeta[0];
    const float bulk = zeta + eta * (1.0f / 3.0f);
    const float c1 = 2.0f * dx * dx;
    const float c2 = 2.0f * dt * dx;
    const float c3 = 4.0f * dt;
    const float c4 = 2.0f * dt;

    // XCD-chunked bijective swizzle: grid=7812, q=976, r=4.
    // HW round-robins blockIdx across 8 XCDs; remap so XCD k processes a
    // contiguous logical chunk (~= one batch b per XCD).
    const int i = blockIdx.x;
    const int xcd = i & 7;
    const int slot = i >> 3;
    const int lb = (xcd < 4) ? xcd * 977 + slot
                             : 3908 + (xcd - 4) * 976 + slot;

    const int tid = lb * 256 + threadIdx.x;
    const int j = tid & 31;            // y-group: outputs y = 1+4j .. 4+4j
    int r = tid >> 5;
    const int xp = r % 126; r /= 126;
    const int tp = r % 62;  const int b = r / 62;
    const int x = xp + 1, t = tp + 1;
    const int yb = 1 + 4 * j;

    const size_t plane = 16384;                 // 128*128
    const size_t cstr  = (size_t)64 * plane;    // per-channel stride

    const float* base = vars + (size_t)b * 4 * cstr + (size_t)t * plane
                      + ((size_t)x << 7) + yb;
    const float* R0 = base;
    const float* U0 = base + cstr;
    const float* V0 = base + 2 * cstr;
    const float* P0 = base + 3 * cstr;

    const float mLo = (j == 0)  ? 0.0f : 1.0f;   // y' = -1 reads 0
    const float mHi = (j == 31) ? 0.0f : 1.0f;   // y' >= 128 reads 0

#define WIN(ptr, off, lo, hi) \
    vf4 lo = ld4((ptr) + (off) - 2); vf4 hi = ld4((ptr) + (off) + 2); \
    lo[0] *= mLo; hi[1] *= mHi; hi[2] *= mHi; hi[3] *= mHi;

    WIN(R0, 0,    r0lo, r0hi)
    WIN(U0, 0,    u0lo, u0hi)
    WIN(U0, 128,  uplo, uphi)
    WIN(U0, -128, umlo, umhi)
    WIN(V0, 0,    v0lo, v0hi)
    WIN(V0, 128,  vplo, vphi)
    WIN(V0, -128, vmlo, vmhi)
    WIN(P0, 0,    p0lo, p0hi)
#undef WIN

    const vf4 rxp = ld4(R0 + 128), rxm = ld4(R0 - 128);
    const vf4 rtp = ld4(R0 + plane), rtm = ld4(R0 - plane);
    const vf4 utp = ld4(U0 + plane), utm = ld4(U0 - plane);
    const vf4 vtp = ld4(V0 + plane), vtm = ld4(V0 - plane);
    const vf4 pxp = ld4(P0 + 128), pxm = ld4(P0 - 128);
    const vf4 zero = {0.0f, 0.0f, 0.0f, 0.0f};
    const vf4 uxp2 = (x <= 125) ? ld4(U0 + 256) : zero;
    const vf4 uxm2 = (x >= 2)   ? ld4(U0 - 256) : zero;

    const vf4 rho = SH(r0lo, r0hi, 0);
    const vf4 u   = SH(u0lo, u0hi, 0);
    const vf4 v   = SH(v0lo, v0hi, 0);

    const vf4 uxp = SH(uplo, uphi, 0), uxm = SH(umlo, umhi, 0);
    const vf4 uyp = SH(u0lo, u0hi, 1), uym = SH(u0lo, u0hi, -1);
    const vf4 vxp = SH(vplo, vphi, 0), vxm = SH(vmlo, vmhi, 0);
    const vf4 vyp = SH(v0lo, v0hi, 1), vym = SH(v0lo, v0hi, -1);

    const vf4 Dt_rho = rtp - rtm;
    const vf4 Dx_rho = rxp - rxm;
    const vf4 Dy_rho = SH(r0lo, r0hi, 1) - SH(r0lo, r0hi, -1);
    const vf4 Dx_u = uxp - uxm, Dy_u = uyp - uym;
    const vf4 Dx_v = vxp - vxm, Dy_v = vyp - vym;

    const vf4 mass = Dt_rho * dx + rho * (Dx_u + Dy_v) * dt
                   + u * Dx_rho * dt + v * Dy_rho * dt;

    const vf4 Dt_u = utp - utm, Dt_v = vtp - vtm;
    const vf4 Dx_p = pxp - pxm;
    const vf4 Dy_p = SH(p0lo, p0hi, 1) - SH(p0lo, p0hi, -1);
    const vf4 lap_u = uxp + uxm + uyp + uym - 4.0f * u;
    const vf4 lap_v = vxp + vxm + vyp + vym - 4.0f * v;

    const vf4 Dx_div = uxp2 - 2.0f * u + uxm2
                     + SH(vplo, vphi, 1) - SH(vplo, vphi, -1)
                     - SH(vmlo, vmhi, 1) + SH(vmlo, vmhi, -1);
    const vf4 Dy_div = SH(v0lo, v0hi, 2) - 2.0f * v + SH(v0lo, v0hi, -2)
                     + SH(uplo, uphi, 1) - SH(umlo, umhi, 1)
                     - SH(uplo, uphi, -1) + SH(umlo, umhi, -1);

    const vf4 mom = rho * (Dt_u + Dt_v) * c1
                  + (u * Dx_u + v * Dy_u + u * Dx_v + v * Dy_v) * c2
                  + (Dx_p + Dy_p) * c2
                  - eta * (lap_u + lap_v) * c3
                  - bulk * (Dx_div + Dy_div) * c4;

    const size_t oplane = 126 * 126;
    const size_t ocstr  = (size_t)62 * oplane;
    float* o1 = out + (size_t)b * 2 * ocstr + (size_t)tp * oplane
              + (size_t)xp * 126 + 4 * j;
    float* o2 = o1 + ocstr;
    if (j < 31) {
        __builtin_nontemporal_store(mass, reinterpret_cast<vf4u*>(o1));
        __builtin_nontemporal_store(mom,  reinterpret_cast<vf4u*>(o2));
    } else {  // outputs y=127,128 out of range; store only 2
        __builtin_nontemporal_store(mass[0], o1);
        __builtin_nontemporal_store(mass[1], o1 + 1);
        __builtin_nontemporal_store(mom[0],  o2);
        __builtin_nontemporal_store(mom[1],  o2 + 1);
    }
}

extern "C" void kernel_launch(void* const* d_in, const int* in_sizes, int n_in,
                              void* d_out, int out_size, void* d_ws, size_t ws_size,
                              hipStream_t stream) {
    const float* vars   = (const float*)d_in[0];
    const float* s_dx   = (const float*)d_in[1];
    const float* s_dt   = (const float*)d_in[2];
    const float* s_eta  = (const float*)d_in[3];
    const float* s_zeta = (const float*)d_in[4];
    float* out = (float*)d_out;

    const int grid = 7812;  // 8*62*126*32 threads / 256
    hipLaunchKernelGGL(cns_residuals_kernel, dim3(grid), dim3(256), 0, stream,
                       vars, s_dx, s_dt, s_eta, s_zeta, out);
}